// Round 8
// baseline (203.098 us; speedup 1.0000x reference)
//
#include <hip/hip_runtime.h>

typedef _Float16 f16;
typedef f16 f16x8 __attribute__((ext_vector_type(8)));
typedef f16 f16x4 __attribute__((ext_vector_type(4)));
typedef __fp16 h16x2 __attribute__((ext_vector_type(2)));   // cvt_pkrtz native type
typedef float f32x4 __attribute__((ext_vector_type(4)));
typedef float f32x2 __attribute__((ext_vector_type(2)));

#define MFMA16(A, B, C) __builtin_amdgcn_mfma_f32_16x16x32_f16((A), (B), (C), 0, 0, 0)

// Barrier WITHOUT vmcnt drain: only LDS (lgkmcnt) must be visible across it.
// __syncthreads() emits s_waitcnt vmcnt(0) and would serialize the in-flight
// x prefetch into the critical path every iteration.
#define LDS_BARRIER() asm volatile("s_waitcnt lgkmcnt(0)\n\ts_barrier" ::: "memory")

__device__ __forceinline__ float E2(float x) {   // 2^x
#if __has_builtin(__builtin_amdgcn_exp2f)
  return __builtin_amdgcn_exp2f(x);
#else
  return __expf(x * 0.69314718056f);
#endif
}

__device__ __forceinline__ f16x8 cvt8(float4 a, float4 b) {
  union { h16x2 h[4]; f16x8 v; } u;
  u.h[0] = __builtin_amdgcn_cvt_pkrtz(a.x, a.y);
  u.h[1] = __builtin_amdgcn_cvt_pkrtz(a.z, a.w);
  u.h[2] = __builtin_amdgcn_cvt_pkrtz(b.x, b.y);
  u.h[3] = __builtin_amdgcn_cvt_pkrtz(b.z, b.w);
  return u.v;
}

// Packed gate math for a pair of h-rows.  float2 ops -> v_pk_*_f32.
// sigmoid pair shares one rcp; tanh(y) = (1-c)*rcp(1+c), c = 2^(-2*log2e*y).
__device__ __forceinline__ void gates_pair(f32x2 aR, f32x2 aZ, f32x2 aXN,
                                           f32x2 aHN, f32x2& hs) {
  const float K = -1.44269504f;  // -log2(e)
  f32x2 mR = aR * K;
  f32x2 mZ = aZ * K;
  f32x2 ea, eb;
  ea[0] = E2(mR[0]); ea[1] = E2(mR[1]);
  eb[0] = E2(mZ[0]); eb[1] = E2(mZ[1]);
  f32x2 pa = ea + 1.0f;
  f32x2 pb = eb + 1.0f;
  f32x2 prod = pa * pb;
  f32x2 inv;
  inv[0] = __builtin_amdgcn_rcpf(prod[0]);
  inv[1] = __builtin_amdgcn_rcpf(prod[1]);
  f32x2 rg = pb * inv;                 // sigmoid(aR)
  f32x2 zg = pa * inv;                 // sigmoid(aZ)
  f32x2 y = rg * aHN + aXN;
  f32x2 my = y * (2.0f * K);           // -2*log2e*y
  f32x2 c;
  c[0] = E2(my[0]); c[1] = E2(my[1]);
  f32x2 num = 1.0f - c;
  f32x2 den = 1.0f + c;
  f32x2 rin;
  rin[0] = __builtin_amdgcn_rcpf(den[0]);
  rin[1] = __builtin_amdgcn_rcpf(den[1]);
  f32x2 ng = num * rin;                // tanh(y)
  hs = zg * (hs - ng) + ng;
}

// B=4096, T=128, D=32, H=64.  16 batch / WG, FOUR waves (R8: fat waves).
// Waves 0-1 (group A): layer 0, step t.  Waves 2-3 (group B): layer 1, t-1.
// Each wave owns 6 row-tiles (h-rows [32w,32w+32), r/z/n each) -> grid 256 x
// 4 waves = 1 wave/SIMD: no intra-SIMD issue contention, 4-wave barrier,
// latency hidden by intra-wave ILP (6 MFMA streams, 4 gate-pair chains).
// Time loop unrolled x2 (compile-time ping-pong parity; R4: runtime idx ->
// scratch).  One LDS-only s_barrier per pipeline phase.
// H LDS layout: h[k] for batch b at f16 offset ((k>>3)*16+b)*8 + (k&7)
//   -> B-frag for lane L, kfrag f = stride-1 ds_read_b128 at f*1024 + L*16.
__launch_bounds__(256, 1)
__global__ void gru_fused(const float* __restrict__ x,
                          const float* __restrict__ Wih0, const float* __restrict__ Whh0,
                          const float* __restrict__ bih0, const float* __restrict__ bhh0,
                          const float* __restrict__ Wih1, const float* __restrict__ Whh1,
                          const float* __restrict__ bih1, const float* __restrict__ bhh1,
                          const float* __restrict__ fcw, const float* __restrict__ fcb,
                          float* __restrict__ out) {
  __shared__ f16 H0[2][1024];
  __shared__ f16 H1[2][1024];
  __shared__ float red[2][16];

  const int tid = threadIdx.x;
  const int wave = tid >> 6;
  const int lane = tid & 63;
  const int l15 = lane & 15;
  const int q = lane >> 4;
  const int w = wave & 1;        // half index within group
  const bool isB = wave >= 2;
  const int b0 = blockIdx.x * 16;

  for (int i = tid; i < 2048; i += 256) {
    ((f16*)H0)[i] = (f16)0.0f;
    ((f16*)H1)[i] = (f16)0.0f;
  }

  // ---- register-resident weight A-fragments: A[m=l15][k = kf*32 + q*8 + j]
  // wave owns h-rows [32w,32w+32): row-tiles at 32w+16u, u in {0,1}.
  f16x8 wAx[3][2];       // layer0 Wih (K=32)  [g][u]       — group A only
  f16x8 wAh[3][2][2];    // layer0 Whh (K=64)  [g][u][kf]   — group A only
  f16x8 wBx[3][2][2];    // layer1 Wih (K=64)  [g][u][kf]   — group B only
  f16x8 wBh[3][2][2];    // layer1 Whh (K=64)  [g][u][kf]   — group B only
  f32x4 bRu[2], bZu[2], bXNu[2], bHNu[2];
  float fw[2][4] = {{0.f, 0.f, 0.f, 0.f}, {0.f, 0.f, 0.f, 0.f}};

  if (!isB) {
#pragma unroll
    for (int g = 0; g < 3; ++g) {
#pragma unroll
      for (int u = 0; u < 2; ++u) {
        const int row = g * 64 + 32 * w + 16 * u + l15;
        const float* p = Wih0 + row * 32 + q * 8;
        wAx[g][u] = cvt8(*(const float4*)p, *(const float4*)(p + 4));
#pragma unroll
        for (int kf = 0; kf < 2; ++kf) {
          const float* ph = Whh0 + row * 64 + kf * 32 + q * 8;
          wAh[g][u][kf] = cvt8(*(const float4*)ph, *(const float4*)(ph + 4));
        }
      }
    }
#pragma unroll
    for (int u = 0; u < 2; ++u)
#pragma unroll
      for (int r = 0; r < 4; ++r) {
        const int o = 32 * w + 16 * u + 4 * q + r;
        bRu[u][r] = bih0[o] + bhh0[o];
        bZu[u][r] = bih0[64 + o] + bhh0[64 + o];
        bXNu[u][r] = bih0[128 + o];
        bHNu[u][r] = bhh0[128 + o];
      }
  } else {
#pragma unroll
    for (int g = 0; g < 3; ++g) {
#pragma unroll
      for (int u = 0; u < 2; ++u) {
        const int row = g * 64 + 32 * w + 16 * u + l15;
#pragma unroll
        for (int kf = 0; kf < 2; ++kf) {
          const float* p1 = Wih1 + row * 64 + kf * 32 + q * 8;
          wBx[g][u][kf] = cvt8(*(const float4*)p1, *(const float4*)(p1 + 4));
          const float* p2 = Whh1 + row * 64 + kf * 32 + q * 8;
          wBh[g][u][kf] = cvt8(*(const float4*)p2, *(const float4*)(p2 + 4));
        }
      }
    }
#pragma unroll
    for (int u = 0; u < 2; ++u)
#pragma unroll
      for (int r = 0; r < 4; ++r) {
        const int o = 32 * w + 16 * u + 4 * q + r;
        bRu[u][r] = bih1[o] + bhh1[o];
        bZu[u][r] = bih1[64 + o] + bhh1[64 + o];
        bXNu[u][r] = bih1[128 + o];
        bHNu[u][r] = bhh1[128 + o];
        fw[u][r] = fcw[o];
      }
  }
  const float fcb0 = fcb[0];

  // this lane's 8 h rows (own layer): hs01[u] = rows 4q+{0,1}, hs23[u] = 4q+{2,3}
  f32x2 hs01[2] = {{0.f, 0.f}, {0.f, 0.f}};
  f32x2 hs23[2] = {{0.f, 0.f}, {0.f, 0.f}};

  // f16 offsets of this lane's two b64 h-stores (u=0,1)
  int widxu[2];
#pragma unroll
  for (int u = 0; u < 2; ++u) {
    const int wk0 = 32 * w + 16 * u + 4 * q;
    widxu[u] = ((wk0 >> 3) * 16 + l15) * 8 + (wk0 & 7);
  }

  // layer-0 step: read H0r, consume x frag, write H0w
  auto stepA = [&](const f16* H0r, f16* H0w, float4 xav, float4 xbv) {
    const f16x8 xf = cvt8(xav, xbv);
    const f16x8 h0f0 = *(const f16x8*)&H0r[lane * 8];
    const f16x8 h0f1 = *(const f16x8*)&H0r[512 + lane * 8];
#pragma unroll
    for (int u = 0; u < 2; ++u) {
      f32x4 aR = MFMA16(wAx[0][u], xf, bRu[u]);
      f32x4 aZ = MFMA16(wAx[1][u], xf, bZu[u]);
      f32x4 aXN = MFMA16(wAx[2][u], xf, bXNu[u]);
      f32x4 aHN = MFMA16(wAh[2][u][0], h0f0, bHNu[u]);
      aR = MFMA16(wAh[0][u][0], h0f0, aR);
      aZ = MFMA16(wAh[1][u][0], h0f0, aZ);
      aR = MFMA16(wAh[0][u][1], h0f1, aR);
      aZ = MFMA16(wAh[1][u][1], h0f1, aZ);
      aHN = MFMA16(wAh[2][u][1], h0f1, aHN);
      gates_pair(f32x2{aR[0], aR[1]}, f32x2{aZ[0], aZ[1]},
                 f32x2{aXN[0], aXN[1]}, f32x2{aHN[0], aHN[1]}, hs01[u]);
      gates_pair(f32x2{aR[2], aR[3]}, f32x2{aZ[2], aZ[3]},
                 f32x2{aXN[2], aXN[3]}, f32x2{aHN[2], aHN[3]}, hs23[u]);
      union { h16x2 h2[2]; f16x4 v; } uw;
      uw.h2[0] = __builtin_amdgcn_cvt_pkrtz(hs01[u][0], hs01[u][1]);
      uw.h2[1] = __builtin_amdgcn_cvt_pkrtz(hs23[u][0], hs23[u][1]);
      *(f16x4*)&H0w[widxu[u]] = uw.v;
    }
  };

  // layer-1 step: read h0 from H0r, own state from H1r, write H1w
  auto stepB = [&](const f16* H0r, const f16* H1r, f16* H1w) {
    const f16x8 g0 = *(const f16x8*)&H0r[lane * 8];
    const f16x8 g1 = *(const f16x8*)&H0r[512 + lane * 8];
    const f16x8 h1f0 = *(const f16x8*)&H1r[lane * 8];
    const f16x8 h1f1 = *(const f16x8*)&H1r[512 + lane * 8];
#pragma unroll
    for (int u = 0; u < 2; ++u) {
      f32x4 aR = MFMA16(wBx[0][u][0], g0, bRu[u]);
      f32x4 aZ = MFMA16(wBx[1][u][0], g0, bZu[u]);
      f32x4 aXN = MFMA16(wBx[2][u][0], g0, bXNu[u]);
      f32x4 aHN = MFMA16(wBh[2][u][0], h1f0, bHNu[u]);
      aR = MFMA16(wBx[0][u][1], g1, aR);
      aZ = MFMA16(wBx[1][u][1], g1, aZ);
      aXN = MFMA16(wBx[2][u][1], g1, aXN);
      aHN = MFMA16(wBh[2][u][1], h1f1, aHN);
      aR = MFMA16(wBh[0][u][0], h1f0, aR);
      aZ = MFMA16(wBh[1][u][0], h1f0, aZ);
      aR = MFMA16(wBh[0][u][1], h1f1, aR);
      aZ = MFMA16(wBh[1][u][1], h1f1, aZ);
      gates_pair(f32x2{aR[0], aR[1]}, f32x2{aZ[0], aZ[1]},
                 f32x2{aXN[0], aXN[1]}, f32x2{aHN[0], aHN[1]}, hs01[u]);
      gates_pair(f32x2{aR[2], aR[3]}, f32x2{aZ[2], aZ[3]},
                 f32x2{aXN[2], aXN[3]}, f32x2{aHN[2], aHN[3]}, hs23[u]);
      union { h16x2 h2[2]; f16x4 v; } uw;
      uw.h2[0] = __builtin_amdgcn_cvt_pkrtz(hs01[u][0], hs01[u][1]);
      uw.h2[1] = __builtin_amdgcn_cvt_pkrtz(hs23[u][0], hs23[u][1]);
      *(f16x4*)&H1w[widxu[u]] = uw.v;
    }
  };

  __syncthreads();

  // x B-frag source (group A only): lane (l15,q) reads x[b0+l15][t][q*8..q*8+7]
  // 2-deep prefetch in STATICALLY NAMED registers (slot0 = even t, slot1 = odd).
  const float* xbase = x + (size_t)(b0 + l15) * 4096 + q * 8;
  float4 xa0, xb0, xa1, xb1;
  if (!isB) {
    xa0 = *(const float4*)xbase;
    xb0 = *(const float4*)(xbase + 4);
    xa1 = *(const float4*)(xbase + 32);
    xb1 = *(const float4*)(xbase + 36);
  }

  for (int t = 0; t < 128; t += 2) {
    // ---- pipeline phase t (parity 0): A step t, B step t-1
    if (!isB) {
      const float4 cxa = xa0, cxb = xb0;
      if (t + 2 < 128) {
        const float* xp = xbase + (t + 2) * 32;
        xa0 = *(const float4*)xp;
        xb0 = *(const float4*)(xp + 4);
      }
      stepA(H0[0], H0[1], cxa, cxb);
    } else if (t > 0) {
      stepB(H0[0], H1[0], H1[1]);
    }
    LDS_BARRIER();

    // ---- pipeline phase t+1 (parity 1): A step t+1, B step t
    if (!isB) {
      const float4 cxa = xa1, cxb = xb1;
      if (t + 3 < 128) {
        const float* xp = xbase + (t + 3) * 32;
        xa1 = *(const float4*)xp;
        xb1 = *(const float4*)(xp + 4);
      }
      stepA(H0[1], H0[0], cxa, cxb);
    } else {
      stepB(H0[1], H1[1], H1[0]);
    }
    LDS_BARRIER();
  }
  // ---- pipeline phase t=128 (parity 0): B step 127 only
  if (isB) stepB(H0[0], H1[0], H1[1]);

  // ---- fc: out[b] = sum_i h1[i]*fcw[i] + fcb   (group B holds h1(127))
  if (isB) {
    float partial = 0.f;
#pragma unroll
    for (int u = 0; u < 2; ++u)
      partial += fw[u][0] * hs01[u][0] + fw[u][1] * hs01[u][1] +
                 fw[u][2] * hs23[u][0] + fw[u][3] * hs23[u][1];
    partial += __shfl_down(partial, 16, 64);
    partial += __shfl_down(partial, 32, 64);
    if (lane < 16) red[w][l15] = partial;
  }
  __syncthreads();
  if (tid < 16) out[b0 + tid] = red[0][tid] + red[1][tid] + fcb0;
}

extern "C" void kernel_launch(void* const* d_in, const int* in_sizes, int n_in,
                              void* d_out, int out_size, void* d_ws, size_t ws_size,
                              hipStream_t stream) {
  (void)in_sizes; (void)n_in; (void)out_size; (void)d_ws; (void)ws_size;
  const float* x    = (const float*)d_in[0];
  const float* Wih0 = (const float*)d_in[1];
  const float* Whh0 = (const float*)d_in[2];
  const float* bih0 = (const float*)d_in[3];
  const float* bhh0 = (const float*)d_in[4];
  const float* Wih1 = (const float*)d_in[5];
  const float* Whh1 = (const float*)d_in[6];
  const float* bih1 = (const float*)d_in[7];
  const float* bhh1 = (const float*)d_in[8];
  const float* fcw  = (const float*)d_in[9];
  const float* fcb  = (const float*)d_in[10];
  float* out = (float*)d_out;

  gru_fused<<<256, 256, 0, stream>>>(x, Wih0, Whh0, bih0, bhh0,
                                     Wih1, Whh1, bih1, bhh1, fcw, fcb, out);
}

// Round 9
// 188.541 us; speedup vs baseline: 1.0772x; 1.0772x over previous
//
#include <hip/hip_runtime.h>

typedef _Float16 f16;
typedef f16 f16x8 __attribute__((ext_vector_type(8)));
typedef f16 f16x4 __attribute__((ext_vector_type(4)));
typedef __fp16 h16x2 __attribute__((ext_vector_type(2)));   // cvt_pkrtz native type
typedef float f32x4 __attribute__((ext_vector_type(4)));
typedef float f32x2 __attribute__((ext_vector_type(2)));

#define MFMA16(A, B, C) __builtin_amdgcn_mfma_f32_16x16x32_f16((A), (B), (C), 0, 0, 0)

// Barrier WITHOUT vmcnt drain: only LDS (lgkmcnt) must be visible across it.
#define LDS_BARRIER() asm volatile("s_waitcnt lgkmcnt(0)\n\ts_barrier" ::: "memory")

__device__ __forceinline__ float E2(float x) {   // 2^x
#if __has_builtin(__builtin_amdgcn_exp2f)
  return __builtin_amdgcn_exp2f(x);
#else
  return __expf(x * 0.69314718056f);
#endif
}

__device__ __forceinline__ f16x8 cvt8(float4 a, float4 b) {
  union { h16x2 h[4]; f16x8 v; } u;
  u.h[0] = __builtin_amdgcn_cvt_pkrtz(a.x, a.y);
  u.h[1] = __builtin_amdgcn_cvt_pkrtz(a.z, a.w);
  u.h[2] = __builtin_amdgcn_cvt_pkrtz(b.x, b.y);
  u.h[3] = __builtin_amdgcn_cvt_pkrtz(b.z, b.w);
  return u.v;
}

// Packed gate math for a pair of h-rows (proven in R6/R7, absmax 3.9e-3).
__device__ __forceinline__ void gates_pair(f32x2 aR, f32x2 aZ, f32x2 aXN,
                                           f32x2 aHN, f32x2& hs) {
  const float K = -1.44269504f;  // -log2(e)
  f32x2 mR = aR * K;
  f32x2 mZ = aZ * K;
  f32x2 ea, eb;
  ea[0] = E2(mR[0]); ea[1] = E2(mR[1]);
  eb[0] = E2(mZ[0]); eb[1] = E2(mZ[1]);
  f32x2 pa = ea + 1.0f;
  f32x2 pb = eb + 1.0f;
  f32x2 prod = pa * pb;
  f32x2 inv;
  inv[0] = __builtin_amdgcn_rcpf(prod[0]);
  inv[1] = __builtin_amdgcn_rcpf(prod[1]);
  f32x2 rg = pb * inv;                 // sigmoid(aR)
  f32x2 zg = pa * inv;                 // sigmoid(aZ)
  f32x2 y = rg * aHN + aXN;
  f32x2 my = y * (2.0f * K);           // -2*log2e*y
  f32x2 c;
  c[0] = E2(my[0]); c[1] = E2(my[1]);
  f32x2 num = 1.0f - c;
  f32x2 den = 1.0f + c;
  f32x2 rin;
  rin[0] = __builtin_amdgcn_rcpf(den[0]);
  rin[1] = __builtin_amdgcn_rcpf(den[1]);
  f32x2 ng = num * rin;                // tanh(y)
  hs = zg * (hs - ng) + ng;
}

// B=4096, T=128, D=32, H=64.  16 batch / WG, FOUR waves, MERGED ROLES (R9):
// every wave computes layer-0 rows [16w,16w+16) step t AND layer-1 rows
// [16w,16w+16) step t-1 in each phase -> two independent dependency chains
// per wave (A-chain stall filled by B-chain issue).  B's h0(t-1) input
// fragments are the same registers A loads (both read H0[p]): LDS reads
// drop 24->16 b128 per CU-phase.  4-wave lgkm-only barrier per phase.
// H LDS layout: h[k] for batch b at f16 offset ((k>>3)*16+b)*8 + (k&7)
//   -> B-frag for lane L, kfrag f = stride-1 ds_read_b128 at f*1024 + L*16.
__launch_bounds__(256, 1)
__global__ void gru_fused(const float* __restrict__ x,
                          const float* __restrict__ Wih0, const float* __restrict__ Whh0,
                          const float* __restrict__ bih0, const float* __restrict__ bhh0,
                          const float* __restrict__ Wih1, const float* __restrict__ Whh1,
                          const float* __restrict__ bih1, const float* __restrict__ bhh1,
                          const float* __restrict__ fcw, const float* __restrict__ fcb,
                          float* __restrict__ out) {
  __shared__ f16 H0[2][1024];
  __shared__ f16 H1[2][1024];
  __shared__ float red[4][16];

  const int tid = threadIdx.x;
  const int w = tid >> 6;          // wave 0..3
  const int lane = tid & 63;
  const int l15 = lane & 15;
  const int q = lane >> 4;
  const int b0 = blockIdx.x * 16;

  for (int i = tid; i < 2048; i += 256) {
    ((f16*)H0)[i] = (f16)0.0f;
    ((f16*)H1)[i] = (f16)0.0f;
  }

  // ---- register-resident weights for BOTH layers, rows 16w..16w+15.
  //      A-frag layout: A[m=l15][k = kf*32 + q*8 + j]
  f16x8 wAx[3];          // layer0 Wih (K=32)
  f16x8 wAh[3][2];       // layer0 Whh (K=64)
  f16x8 wBx[3][2];       // layer1 Wih (K=64)
  f16x8 wBh[3][2];       // layer1 Whh (K=64)
#pragma unroll
  for (int g = 0; g < 3; ++g) {
    const int row = g * 64 + 16 * w + l15;
    const float* p = Wih0 + row * 32 + q * 8;
    wAx[g] = cvt8(*(const float4*)p, *(const float4*)(p + 4));
#pragma unroll
    for (int kf = 0; kf < 2; ++kf) {
      const float* ph = Whh0 + row * 64 + kf * 32 + q * 8;
      wAh[g][kf] = cvt8(*(const float4*)ph, *(const float4*)(ph + 4));
      const float* p1 = Wih1 + row * 64 + kf * 32 + q * 8;
      wBx[g][kf] = cvt8(*(const float4*)p1, *(const float4*)(p1 + 4));
      const float* p2 = Whh1 + row * 64 + kf * 32 + q * 8;
      wBh[g][kf] = cvt8(*(const float4*)p2, *(const float4*)(p2 + 4));
    }
  }

  f32x4 bR0, bZ0, bXN0, bHN0, bR1, bZ1, bXN1, bHN1;
  float fw[4];
#pragma unroll
  for (int r = 0; r < 4; ++r) {
    const int o = 16 * w + 4 * q + r;
    bR0[r] = bih0[o] + bhh0[o];
    bZ0[r] = bih0[64 + o] + bhh0[64 + o];
    bXN0[r] = bih0[128 + o];
    bHN0[r] = bhh0[128 + o];
    bR1[r] = bih1[o] + bhh1[o];
    bZ1[r] = bih1[64 + o] + bhh1[64 + o];
    bXN1[r] = bih1[128 + o];
    bHN1[r] = bhh1[128 + o];
    fw[r] = fcw[o];
  }
  const float fcb0 = fcb[0];

  // states: layer0 rows 4q+{0,1},{2,3} and layer1 ditto
  f32x2 h0s01 = {0.f, 0.f}, h0s23 = {0.f, 0.f};
  f32x2 h1s01 = {0.f, 0.f}, h1s23 = {0.f, 0.f};

  const int wk0 = 16 * w + 4 * q;
  const int widx = ((wk0 >> 3) * 16 + l15) * 8 + (wk0 & 7); // b64 store offset

  // merged phase: A = layer0 step t (consume xf), B = layer1 step t-1.
  auto phase = [&](const f16* H0r, f16* H0w, const f16* H1r, f16* H1w,
                   float4 xav, float4 xbv, bool doB) {
    const f16x8 h0f0 = *(const f16x8*)&H0r[lane * 8];
    const f16x8 h0f1 = *(const f16x8*)&H0r[512 + lane * 8];
    const f16x8 xf = cvt8(xav, xbv);
    // ---- A MFMAs (x-part issues immediately; LDS-dependent after)
    f32x4 aR = MFMA16(wAx[0], xf, bR0);
    f32x4 aZ = MFMA16(wAx[1], xf, bZ0);
    f32x4 aXN = MFMA16(wAx[2], xf, bXN0);
    f32x4 aHN = MFMA16(wAh[2][0], h0f0, bHN0);
    aR = MFMA16(wAh[0][0], h0f0, aR);
    aZ = MFMA16(wAh[1][0], h0f0, aZ);
    aR = MFMA16(wAh[0][1], h0f1, aR);
    aZ = MFMA16(wAh[1][1], h0f1, aZ);
    aHN = MFMA16(wAh[2][1], h0f1, aHN);
    if (doB) {
      const f16x8 h1f0 = *(const f16x8*)&H1r[lane * 8];
      const f16x8 h1f1 = *(const f16x8*)&H1r[512 + lane * 8];
      // ---- B MFMAs (inputs: h0f* shared with A, plus own h1 state)
      f32x4 cR = MFMA16(wBx[0][0], h0f0, bR1);
      f32x4 cZ = MFMA16(wBx[1][0], h0f0, bZ1);
      f32x4 cXN = MFMA16(wBx[2][0], h0f0, bXN1);
      f32x4 cHN = MFMA16(wBh[2][0], h1f0, bHN1);
      cR = MFMA16(wBx[0][1], h0f1, cR);
      cZ = MFMA16(wBx[1][1], h0f1, cZ);
      cXN = MFMA16(wBx[2][1], h0f1, cXN);
      cHN = MFMA16(wBh[2][1], h1f1, cHN);
      cR = MFMA16(wBh[0][0], h1f0, cR);
      cZ = MFMA16(wBh[1][0], h1f0, cZ);
      cR = MFMA16(wBh[0][1], h1f1, cR);
      cZ = MFMA16(wBh[1][1], h1f1, cZ);
      // ---- A gates + h0 store (overlaps B MFMA latency)
      gates_pair(f32x2{aR[0], aR[1]}, f32x2{aZ[0], aZ[1]},
                 f32x2{aXN[0], aXN[1]}, f32x2{aHN[0], aHN[1]}, h0s01);
      gates_pair(f32x2{aR[2], aR[3]}, f32x2{aZ[2], aZ[3]},
                 f32x2{aXN[2], aXN[3]}, f32x2{aHN[2], aHN[3]}, h0s23);
      union { h16x2 h2[2]; f16x4 v; } uw0;
      uw0.h2[0] = __builtin_amdgcn_cvt_pkrtz(h0s01[0], h0s01[1]);
      uw0.h2[1] = __builtin_amdgcn_cvt_pkrtz(h0s23[0], h0s23[1]);
      *(f16x4*)&H0w[widx] = uw0.v;
      // ---- B gates + h1 store
      gates_pair(f32x2{cR[0], cR[1]}, f32x2{cZ[0], cZ[1]},
                 f32x2{cXN[0], cXN[1]}, f32x2{cHN[0], cHN[1]}, h1s01);
      gates_pair(f32x2{cR[2], cR[3]}, f32x2{cZ[2], cZ[3]},
                 f32x2{cXN[2], cXN[3]}, f32x2{cHN[2], cHN[3]}, h1s23);
      union { h16x2 h2[2]; f16x4 v; } uw1;
      uw1.h2[0] = __builtin_amdgcn_cvt_pkrtz(h1s01[0], h1s01[1]);
      uw1.h2[1] = __builtin_amdgcn_cvt_pkrtz(h1s23[0], h1s23[1]);
      *(f16x4*)&H1w[widx] = uw1.v;
    } else {
      gates_pair(f32x2{aR[0], aR[1]}, f32x2{aZ[0], aZ[1]},
                 f32x2{aXN[0], aXN[1]}, f32x2{aHN[0], aHN[1]}, h0s01);
      gates_pair(f32x2{aR[2], aR[3]}, f32x2{aZ[2], aZ[3]},
                 f32x2{aXN[2], aXN[3]}, f32x2{aHN[2], aHN[3]}, h0s23);
      union { h16x2 h2[2]; f16x4 v; } uw0;
      uw0.h2[0] = __builtin_amdgcn_cvt_pkrtz(h0s01[0], h0s01[1]);
      uw0.h2[1] = __builtin_amdgcn_cvt_pkrtz(h0s23[0], h0s23[1]);
      *(f16x4*)&H0w[widx] = uw0.v;
    }
  };

  // epilogue-only B step (layer1 step 127)
  auto phaseB = [&](const f16* H0r, const f16* H1r) {
    const f16x8 h0f0 = *(const f16x8*)&H0r[lane * 8];
    const f16x8 h0f1 = *(const f16x8*)&H0r[512 + lane * 8];
    const f16x8 h1f0 = *(const f16x8*)&H1r[lane * 8];
    const f16x8 h1f1 = *(const f16x8*)&H1r[512 + lane * 8];
    f32x4 cR = MFMA16(wBx[0][0], h0f0, bR1);
    f32x4 cZ = MFMA16(wBx[1][0], h0f0, bZ1);
    f32x4 cXN = MFMA16(wBx[2][0], h0f0, bXN1);
    f32x4 cHN = MFMA16(wBh[2][0], h1f0, bHN1);
    cR = MFMA16(wBx[0][1], h0f1, cR);
    cZ = MFMA16(wBx[1][1], h0f1, cZ);
    cXN = MFMA16(wBx[2][1], h0f1, cXN);
    cHN = MFMA16(wBh[2][1], h1f1, cHN);
    cR = MFMA16(wBh[0][0], h1f0, cR);
    cZ = MFMA16(wBh[1][0], h1f0, cZ);
    cR = MFMA16(wBh[0][1], h1f1, cR);
    cZ = MFMA16(wBh[1][1], h1f1, cZ);
    gates_pair(f32x2{cR[0], cR[1]}, f32x2{cZ[0], cZ[1]},
               f32x2{cXN[0], cXN[1]}, f32x2{cHN[0], cHN[1]}, h1s01);
    gates_pair(f32x2{cR[2], cR[3]}, f32x2{cZ[2], cZ[3]},
               f32x2{cXN[2], cXN[3]}, f32x2{cHN[2], cHN[3]}, h1s23);
  };

  __syncthreads();

  // x B-frag source: lane (l15,q) reads x[b0+l15][t][q*8..q*8+7].
  // 2-deep prefetch in statically named registers (slot0 even t, slot1 odd).
  const float* xbase = x + (size_t)(b0 + l15) * 4096 + q * 8;
  float4 xa0 = *(const float4*)xbase;
  float4 xb0 = *(const float4*)(xbase + 4);
  float4 xa1 = *(const float4*)(xbase + 32);
  float4 xb1 = *(const float4*)(xbase + 36);

  for (int t = 0; t < 128; t += 2) {
    {  // phase t (parity 0): A(t), B(t-1)
      const float4 cxa = xa0, cxb = xb0;
      if (t + 2 < 128) {
        const float* xp = xbase + (t + 2) * 32;
        xa0 = *(const float4*)xp;
        xb0 = *(const float4*)(xp + 4);
      }
      phase(H0[0], H0[1], H1[0], H1[1], cxa, cxb, t > 0);
    }
    LDS_BARRIER();
    {  // phase t+1 (parity 1): A(t+1), B(t)
      const float4 cxa = xa1, cxb = xb1;
      if (t + 3 < 128) {
        const float* xp = xbase + (t + 3) * 32;
        xa1 = *(const float4*)xp;
        xb1 = *(const float4*)(xp + 4);
      }
      phase(H0[1], H0[0], H1[1], H1[0], cxa, cxb, true);
    }
    LDS_BARRIER();
  }
  // phase 128 (parity 0): B(127) only
  phaseB(H0[0], H1[0]);

  // ---- fc: out[b] = sum_i h1[i]*fcw[i] + fcb
  {
    float partial = fw[0] * h1s01[0] + fw[1] * h1s01[1] +
                    fw[2] * h1s23[0] + fw[3] * h1s23[1];
    partial += __shfl_down(partial, 16, 64);
    partial += __shfl_down(partial, 32, 64);
    if (lane < 16) red[w][l15] = partial;
  }
  __syncthreads();
  if (tid < 16) out[b0 + tid] = red[0][tid] + red[1][tid] + red[2][tid] + red[3][tid] + fcb0;
}

extern "C" void kernel_launch(void* const* d_in, const int* in_sizes, int n_in,
                              void* d_out, int out_size, void* d_ws, size_t ws_size,
                              hipStream_t stream) {
  (void)in_sizes; (void)n_in; (void)out_size; (void)d_ws; (void)ws_size;
  const float* x    = (const float*)d_in[0];
  const float* Wih0 = (const float*)d_in[1];
  const float* Whh0 = (const float*)d_in[2];
  const float* bih0 = (const float*)d_in[3];
  const float* bhh0 = (const float*)d_in[4];
  const float* Wih1 = (const float*)d_in[5];
  const float* Whh1 = (const float*)d_in[6];
  const float* bih1 = (const float*)d_in[7];
  const float* bhh1 = (const float*)d_in[8];
  const float* fcw  = (const float*)d_in[9];
  const float* fcb  = (const float*)d_in[10];
  float* out = (float*)d_out;

  gru_fused<<<256, 256, 0, stream>>>(x, Wih0, Whh0, bih0, bhh0,
                                     Wih1, Whh1, bih1, bhh1, fcw, fcb, out);
}